// Round 1
// baseline (182.200 us; speedup 1.0000x reference)
//
#include <hip/hip_runtime.h>

// InfoNCE loss:
//   loss = (1/B) * sum_i [ log(sum_j exp(Q_i . D_j / T)) - Q_i . D_{i*dp} / T ]
//
// R5 changes vs R4:
//  - GEMM restructured from 128x128 / 16x16x128 / drain-0 2-barrier loop
//    (m97-structure, MfmaUtil 27%) to 256x256 tile, 8 waves (2x4),
//    mfma_scale_f32_32x32x64_f8f6f4, BK=64, double-buffered 64KB LDS ring
//    with COUNTED s_waitcnt vmcnt(4) (T4) + raw s_barrier + setprio(1)
//    around the MFMA cluster (T5). Next K-tile's global_load_lds stay in
//    flight across the barrier; latency hides under the 8-MFMA cluster.
//  - Pre-tiled fp8 global layout (cvt kernel) UNCHANGED: BK=64 tiles are
//    the kh-halves of the 128-k images; staging is still 1KB lane-linear
//    chunks per global_load_lds (4 per wave per K-tile).
//  - Epilogue re-derived for 32x32 C/D layout:
//    col = lane&31, row = (reg&3) + 8*(reg>>2) + 4*(lane>>5).
//
// Tiled global layout (per matrix, unchanged): for 128-row block R, 128-wide
// k-block k0b: 16KB image = 16 chunks x 1KB. Chunk c = rg*2 + kh (rg=0..7
// 16-row group, kh=0..1 64-col half); slot l (16B) holds
//   X[R*128 + rg*16 + (l&15)][k0b*128 + kh*64 + (l>>4)*16 .. +16]   (fp8)
//
// ws layout (~12.1 MB):
//   [0)       Q8  B*K fp8     (4 MB)
//   [B*K)     D8  N*K fp8     (8 MB)
//   [+N*K)    rowsum B f32    (16 KB)  zeroed by cvt kernel
//   [+B*4)    pos    B f32    (16 KB)  written by gemm epilogue

#define TEMP_INV 50.0f
#define PRESCALE 16.0f
#define SCALE_BYTE 123   // e8m0: 2^(123-127) = 2^-4 per operand

typedef int   i32x4 __attribute__((ext_vector_type(4)));
typedef int   i32x8 __attribute__((ext_vector_type(8)));
typedef float f32x16 __attribute__((ext_vector_type(16)));

// ---------------- fp32 -> fp8 e4m3 (x16), pre-tiled; zero rowsum ----------
__global__ void cvt_kernel(const float* __restrict__ Q, const float* __restrict__ Dm,
                           unsigned int* __restrict__ Q8, unsigned int* __restrict__ D8,
                           float* __restrict__ rowsum, int qSlots, int B, int K) {
    const int gid = blockIdx.x * blockDim.x + threadIdx.x;
    if (gid < B) rowsum[gid] = 0.0f;
    const float* src;
    unsigned int* dst;
    int s;
    if (gid < qSlots) { src = Q;  dst = Q8; s = gid; }
    else              { src = Dm; dst = D8; s = gid - qSlots; }
    const int l   = s & 63;
    const int c   = (s >> 6) & 15;
    const int k0b = (s >> 10) & 7;
    const int R   = s >> 13;
    const int row = R * 128 + (c >> 1) * 16 + (l & 15);
    const int k   = k0b * 128 + (c & 1) * 64 + (l >> 4) * 16;
    const float* p = src + (size_t)row * K + k;
    unsigned int w[4];
#pragma unroll
    for (int d = 0; d < 4; ++d) {
        float4 v = *(const float4*)(p + d * 4);
        int t = __builtin_amdgcn_cvt_pk_fp8_f32(v.x * PRESCALE, v.y * PRESCALE, 0, false);
        t = __builtin_amdgcn_cvt_pk_fp8_f32(v.z * PRESCALE, v.w * PRESCALE, t, true);
        w[d] = (unsigned int)t;
    }
    *(uint4*)(dst + (size_t)s * 4) = make_uint4(w[0], w[1], w[2], w[3]);
}

// ---------------- fused MX-fp8 GEMM + row sum-exp + pos extraction --------
// grid (B/256, N/256), 512 threads (8 waves, 2x4 wave grid), BK=64,
// double-buffered 64KB LDS ring, counted-vmcnt pipeline.
__global__ __launch_bounds__(512, 2) void gemm_expsum_kernel(
        const unsigned int* __restrict__ Q8, const unsigned int* __restrict__ D8,
        const int* __restrict__ dper,
        float* __restrict__ rowsum, float* __restrict__ pos, int K) {
    __shared__ unsigned int BUF[16384];   // 64KB: 2 ring slots x (A 16KB + B 16KB)

    const int tid  = threadIdx.x;
    const int wave = tid >> 6;
    const int lane = tid & 63;
    const int wr   = wave >> 2;          // wave row  (0..1) -> 128 rows
    const int wc   = wave & 3;           // wave col  (0..3) -> 64 cols
    const int lm   = lane & 15;
    const int lh   = (lane >> 4) & 1;
    const int hh   = lane >> 5;
    const int l32  = lane & 31;
    const int bx   = blockIdx.x, by = blockIdx.y;
    const int KB8  = K >> 7;             // global 128-k images per row-block (8)
    const int KT   = K >> 6;             // K-tiles of 64 (16)

    // ---- staging assignment: chunk id flat = wave*4 + q ----
    //  flat 0..15  -> A: rblk = flat>>3, rg = flat&7
    //  flat 16..31 -> B: cblk = (flat>>3)&1, rg = flat&7
    // per K-tile t: image kb = t>>1, k-half kh = t&1 -> chunk (rg*2+kh) of image
    const unsigned int* srcq[4];
    int dofs[4];
#pragma unroll
    for (int q = 0; q < 4; ++q) {
        const int flat = wave * 4 + q;
        const unsigned int* img;
        if (flat < 16)
            img = Q8 + (size_t)(2 * bx + (flat >> 3)) * KB8 * 4096;
        else
            img = D8 + (size_t)(2 * by + ((flat >> 3) & 1)) * KB8 * 4096;
        srcq[q] = img + (flat & 7) * 512 + lane * 4;   // + kb*4096 + kh*256 at stage time
        dofs[q] = flat * 256 + lane * 4;
    }

#define STAGE(t) do { \
    unsigned int* db_ = BUF + ((t) & 1) * 8192; \
    const int so_ = ((t) >> 1) * 4096 + ((t) & 1) * 256; \
    _Pragma("unroll") \
    for (int q = 0; q < 4; ++q) \
        __builtin_amdgcn_global_load_lds( \
            (const __attribute__((address_space(1))) void*)(srcq[q] + so_), \
            (__attribute__((address_space(3))) void*)(db_ + dofs[q]), 16, 0, 0); \
    } while (0)

    // ---- fragment LDS dword offsets (within a ring slot) ----
    // A frag i: rows wr*128 + i*32 + (lane&31), k = (lane>>5)*32 .. +32
    //   -> chunk (wr*8 + i*2 + lh), slots (hh*2, hh*2+1), entry lm
    const int sl4 = (hh * 32 + lm) * 4;
    int aoffs[4], boffs[2];
#pragma unroll
    for (int i = 0; i < 4; ++i)
        aoffs[i] = (wr * 8 + i * 2 + lh) * 256 + sl4;
#pragma unroll
    for (int j = 0; j < 2; ++j)
        boffs[j] = 4096 + ((wc >> 1) * 8 + (wc & 1) * 4 + j * 2 + lh) * 256 + sl4;

    f32x16 acc[8];
#pragma unroll
    for (int t = 0; t < 8; ++t)
#pragma unroll
        for (int e = 0; e < 16; ++e) acc[t][e] = 0.0f;

    // ---- pipelined K loop: prefetch t+1, counted vmcnt, raw barriers ----
    STAGE(0);
    for (int t = 0; t < KT; ++t) {
        if (t + 1 < KT) {
            STAGE(t + 1);
            // 8 loads in flight (tiles t, t+1); wait for tile t's 4 only.
            asm volatile("s_waitcnt vmcnt(4)" ::: "memory");
        } else {
            asm volatile("s_waitcnt vmcnt(0)" ::: "memory");
        }
        __builtin_amdgcn_s_barrier();    // publish tile t cross-wave

        const unsigned int* bp = BUF + (t & 1) * 8192;
        i32x8 a8[4], b8[2];
#pragma unroll
        for (int j = 0; j < 2; ++j) {
            i32x4 lo = *(const i32x4*)(bp + boffs[j]);
            i32x4 hi = *(const i32x4*)(bp + boffs[j] + 64);
            b8[j] = __builtin_shufflevector(lo, hi, 0, 1, 2, 3, 4, 5, 6, 7);
        }
#pragma unroll
        for (int i = 0; i < 4; ++i) {
            i32x4 lo = *(const i32x4*)(bp + aoffs[i]);
            i32x4 hi = *(const i32x4*)(bp + aoffs[i] + 64);
            a8[i] = __builtin_shufflevector(lo, hi, 0, 1, 2, 3, 4, 5, 6, 7);
        }
        __builtin_amdgcn_s_setprio(1);
#pragma unroll
        for (int i = 0; i < 4; ++i)
#pragma unroll
            for (int j = 0; j < 2; ++j)
                acc[i * 2 + j] = __builtin_amdgcn_mfma_scale_f32_32x32x64_f8f6f4(
                    a8[i], b8[j], acc[i * 2 + j], 0, 0, 0, SCALE_BYTE, 0, SCALE_BYTE);
        __builtin_amdgcn_s_setprio(0);
        __builtin_amdgcn_s_barrier();    // tile t fully consumed -> slot reusable
    }
#undef STAGE

    // ---- epilogue. 32x32 C layout: col = lane&31,
    //      row = (reg&3) + 8*(reg>>2) + 4*(lane>>5)
    const int dp  = dper[0];
    const int gr0 = bx * 256 + wr * 128 + 4 * hh;
    const int gc0 = by * 256 + wc * 64 + l32;
#pragma unroll
    for (int i = 0; i < 4; ++i)
#pragma unroll
        for (int r = 0; r < 16; ++r) {
            const int gr = gr0 + i * 32 + (r & 3) + 8 * (r >> 2);
            float e = 0.0f;
#pragma unroll
            for (int j = 0; j < 2; ++j) {
                float v = acc[i * 2 + j][r] * TEMP_INV;
                if (gr * dp == gc0 + j * 32) pos[gr] = v;
                e += __expf(v);
            }
            // sum 32 cols held across the 32-lane half (xor<32 stays in half)
            e += __shfl_xor(e, 1);
            e += __shfl_xor(e, 2);
            e += __shfl_xor(e, 4);
            e += __shfl_xor(e, 8);
            e += __shfl_xor(e, 16);
            if (l32 == 0) atomicAdd(&rowsum[gr], e);
        }
}

// ---------------- final: loss = sum(log(rowsum) - pos)/B ----------------
__global__ void final_kernel(const float* __restrict__ rowsum,
                             const float* __restrict__ pos,
                             float* __restrict__ out, int B) {
    __shared__ float red[16];
    int tid = threadIdx.x;   // 1024 threads
    float s = 0.0f;
    for (int i = tid; i < B; i += blockDim.x)
        s += __logf(rowsum[i]) - pos[i];
    s += __shfl_xor(s, 32);
    s += __shfl_xor(s, 16);
    s += __shfl_xor(s, 8);
    s += __shfl_xor(s, 4);
    s += __shfl_xor(s, 2);
    s += __shfl_xor(s, 1);
    int w = tid >> 6, l = tid & 63;
    if (l == 0) red[w] = s;
    __syncthreads();
    if (tid == 0) {
        float t = 0.0f;
        int nw = blockDim.x >> 6;
        for (int i = 0; i < nw; ++i) t += red[i];
        out[0] = t / (float)B;
    }
}

extern "C" void kernel_launch(void* const* d_in, const int* in_sizes, int n_in,
                              void* d_out, int out_size, void* d_ws, size_t ws_size,
                              hipStream_t stream) {
    const float* Q   = (const float*)d_in[0];
    const float* Dm  = (const float*)d_in[1];
    const int* dper  = (const int*)d_in[2];
    float* out = (float*)d_out;

    const int DIM  = 1024;
    const int B    = in_sizes[0] / DIM;   // 4096
    const int Ntot = in_sizes[1] / DIM;   // 8192

    unsigned int* Q8 = (unsigned int*)d_ws;
    unsigned int* D8 = Q8 + (size_t)B * DIM / 4;
    float* rowsum = (float*)(D8 + (size_t)Ntot * DIM / 4);
    float* pos = rowsum + B;

    const int qSlots = B * DIM / 16;            // 262144
    const int dSlots = Ntot * DIM / 16;         // 524288
    cvt_kernel<<<(qSlots + dSlots) / 256, 256, 0, stream>>>(
        Q, Dm, Q8, D8, rowsum, qSlots, B, DIM);

    dim3 grid(B / 256, Ntot / 256);
    gemm_expsum_kernel<<<grid, 512, 0, stream>>>(Q8, D8, dper, rowsum, pos, DIM);

    final_kernel<<<1, 1024, 0, stream>>>(rowsum, pos, out, B);
}

// Round 2
// 136.821 us; speedup vs baseline: 1.3317x; 1.3317x over previous
//
#include <hip/hip_runtime.h>

// InfoNCE loss:
//   loss = (1/B) * sum_i [ log(sum_j exp(Q_i . D_j / T)) - Q_i . D_{i*dp} / T ]
//
// R6 = R4 (verified 45.7us gemm, MfmaUtil 27%, absmax 0.0) + two changes:
//
//  1. GEMM: depth-1 prefetch, STATIC double buffer, ONE __syncthreads per
//     K-step.  Order per step: ds_read frags(buf cur) -> STAGE next K-image
//     into buf other -> 16 MFMA -> __syncthreads.  The sync's implicit
//     vmcnt(0) drain now happens AFTER ~1100cy of just-issued MFMA pipe
//     work, so the drain overlaps compute instead of preceding it.
//     K-loop unrolled x2 with four statically distinct __shared__ arrays
//     (Qs0/Ds0/Qs1/Ds1) so stage-writes provably never alias frag-reads ->
//     compiler cannot insert parasitic waits (R5 post-mortem: runtime-parity
//     single buffer + inline-asm counted vmcnt let the compiler serialize;
//     + 64KB/128AGPR monolith dropped occupancy to 1 block/CU -> 120us).
//     Here LDS=64KB but VGPR/AGPR stay at R4 levels -> 2 blocks/CU, the
//     m114 cross-block cover is retained.
//
//  2. cvt: within each 64-slot (1KB) output chunk, permute which THREAD
//     produces which slot (l -> ((l&3)<<4)|(l>>2), a bijection).  Chunk
//     contents are unchanged (row/k and the store offset both derive from
//     the permuted slot id), but 4 consecutive lanes now read 256B
//     contiguous from one row instead of 64B runs at 4KB stride.
//
// Tiled global layout (per matrix, unchanged): for 128-row block R, 128-wide
// k-block k0b: 16KB image = 16 chunks x 1KB. Chunk c = rg*2 + kh (rg=0..7
// 16-row group, kh=0..1 64-col half); slot l (16B) holds
//   X[R*128 + rg*16 + (l&15)][k0b*128 + kh*64 + (l>>4)*16 .. +16]   (fp8)
//
// ws layout (~12.1 MB):
//   [0)       Q8  B*K fp8     (4 MB)
//   [B*K)     D8  N*K fp8     (8 MB)
//   [+N*K)    rowsum B f32    (16 KB)  zeroed by cvt kernel
//   [+B*4)    pos    B f32    (16 KB)  written by gemm epilogue

#define TEMP_INV 50.0f
#define PRESCALE 16.0f
#define SCALE_BYTE 123   // e8m0: 2^(123-127) = 2^-4 per operand

typedef int   i32x4 __attribute__((ext_vector_type(4)));
typedef int   i32x8 __attribute__((ext_vector_type(8)));
typedef float f32x4 __attribute__((ext_vector_type(4)));

// ---------------- fp32 -> fp8 e4m3 (x16), pre-tiled; zero rowsum ----------
__global__ void cvt_kernel(const float* __restrict__ Q, const float* __restrict__ Dm,
                           unsigned int* __restrict__ Q8, unsigned int* __restrict__ D8,
                           float* __restrict__ rowsum, int qSlots, int B, int K) {
    const int gid = blockIdx.x * blockDim.x + threadIdx.x;
    if (gid < B) rowsum[gid] = 0.0f;
    const float* src;
    unsigned int* dst;
    int s;
    if (gid < qSlots) { src = Q;  dst = Q8; s = gid; }
    else              { src = Dm; dst = D8; s = gid - qSlots; }
    // Slot permutation within the 64-slot chunk: thread lane l handles slot
    // ((l&3)<<4)|(l>>2).  Reads coalesce to 256B runs (4 lanes share a row);
    // writes still cover the same contiguous 1KB per wave.
    {
        const int l0 = s & 63;
        s = (s & ~63) | (((l0 & 3) << 4) | (l0 >> 2));
    }
    const int l   = s & 63;
    const int c   = (s >> 6) & 15;
    const int k0b = (s >> 10) & 7;
    const int R   = s >> 13;
    const int row = R * 128 + (c >> 1) * 16 + (l & 15);
    const int k   = k0b * 128 + (c & 1) * 64 + (l >> 4) * 16;
    const float* p = src + (size_t)row * K + k;
    unsigned int w[4];
#pragma unroll
    for (int d = 0; d < 4; ++d) {
        float4 v = *(const float4*)(p + d * 4);
        int t = __builtin_amdgcn_cvt_pk_fp8_f32(v.x * PRESCALE, v.y * PRESCALE, 0, false);
        t = __builtin_amdgcn_cvt_pk_fp8_f32(v.z * PRESCALE, v.w * PRESCALE, t, true);
        w[d] = (unsigned int)t;
    }
    *(uint4*)(dst + (size_t)s * 4) = make_uint4(w[0], w[1], w[2], w[3]);
}

// ---------------- fused MX-fp8 GEMM + row sum-exp + pos extraction --------
// grid (B/128, N/128), 256 threads (4 waves, 2x2 wave grid), BK=128,
// depth-1 prefetch across static double buffers, one barrier per K-step.
__global__ __launch_bounds__(256, 2) void gemm_expsum_kernel(
        const unsigned int* __restrict__ Q8, const unsigned int* __restrict__ D8,
        const int* __restrict__ dper,
        float* __restrict__ rowsum, float* __restrict__ pos, int K) {
    __shared__ unsigned int Qs0[4096];   // 16KB fragment-order images
    __shared__ unsigned int Ds0[4096];
    __shared__ unsigned int Qs1[4096];
    __shared__ unsigned int Ds1[4096];

    const int tid   = threadIdx.x;
    const int wave  = tid >> 6;
    const int lane  = tid & 63;
    const int lquad = lane >> 4;
    const int lm    = lane & 15;
    const int qbase = blockIdx.x * 128;
    const int dbase = blockIdx.y * 128;
    const int KB    = K >> 7;           // 8 k-blocks

    // fragment-read dword offsets: chunk(rg, kh=lquad>>1)*256 + slot*4,
    // slot = ((lquad&1)*2 + t)*16 + lm
    const int slotofs = ((lquad & 1) * 32 + lm) * 4;   // t=0; t=1 adds 64
    const int aofs = ((wave >> 1) * 8 + (lquad >> 1)) * 256 + slotofs;
    const int bofs = ((wave & 1) * 8 + (lquad >> 1)) * 256 + slotofs;

    const unsigned int* Qg = Q8 + (size_t)blockIdx.x * KB * 4096;
    const unsigned int* Dg = D8 + (size_t)blockIdx.y * KB * 4096;

    f32x4 acc[16];
#pragma unroll
    for (int t = 0; t < 16; ++t) acc[t] = (f32x4){0.f, 0.f, 0.f, 0.f};

    // stage K-image kb_ into (QD, DD): 8 x global_load_lds(16B) per wave,
    // lane-linear on both sides (1KB contiguous per instr).
#define STAGE(kb_, QD, DD) do {                                              \
    _Pragma("unroll")                                                        \
    for (int q = 0; q < 4; ++q) {                                            \
        const int c_ = wave * 4 + q;                                         \
        __builtin_amdgcn_global_load_lds(                                    \
            (const __attribute__((address_space(1))) void*)(Qg + (kb_) * 4096 + c_ * 256 + lane * 4), \
            (__attribute__((address_space(3))) void*)(QD + c_ * 256 + lane * 4), 16, 0, 0); \
        __builtin_amdgcn_global_load_lds(                                    \
            (const __attribute__((address_space(1))) void*)(Dg + (kb_) * 4096 + c_ * 256 + lane * 4), \
            (__attribute__((address_space(3))) void*)(DD + c_ * 256 + lane * 4), 16, 0, 0); \
    }                                                                        \
} while (0)

    // one K-step: frag-read from (QS,DS); prefetch kb_+1 into (QN,DN);
    // 16 MFMA; single barrier (its vmcnt(0) drain overlaps the MFMA pipe).
#define KSTEP(kb_, QS, DS, QN, DN, doStage) do {                             \
    i32x8 a8[4], b8[4];                                                      \
    _Pragma("unroll")                                                        \
    for (int i = 0; i < 4; ++i) {                                            \
        i32x4 lo = *(const i32x4*)(QS + aofs + i * 512);                     \
        i32x4 hi = *(const i32x4*)(QS + aofs + i * 512 + 64);                \
        a8[i] = __builtin_shufflevector(lo, hi, 0, 1, 2, 3, 4, 5, 6, 7);     \
    }                                                                        \
    _Pragma("unroll")                                                        \
    for (int j = 0; j < 4; ++j) {                                            \
        i32x4 lo = *(const i32x4*)(DS + bofs + j * 512);                     \
        i32x4 hi = *(const i32x4*)(DS + bofs + j * 512 + 64);                \
        b8[j] = __builtin_shufflevector(lo, hi, 0, 1, 2, 3, 4, 5, 6, 7);     \
    }                                                                        \
    if (doStage) STAGE((kb_) + 1, QN, DN);                                   \
    _Pragma("unroll")                                                        \
    for (int i = 0; i < 4; ++i)                                              \
        _Pragma("unroll")                                                    \
        for (int j = 0; j < 4; ++j)                                          \
            acc[i * 4 + j] = __builtin_amdgcn_mfma_scale_f32_16x16x128_f8f6f4( \
                a8[i], b8[j], acc[i * 4 + j], 0, 0, 0, SCALE_BYTE, 0, SCALE_BYTE); \
    __syncthreads();                                                         \
} while (0)

    STAGE(0, Qs0, Ds0);
    __syncthreads();
    for (int kb = 0; kb < KB; kb += 2) {
        KSTEP(kb,     Qs0, Ds0, Qs1, Ds1, true);
        KSTEP(kb + 1, Qs1, Ds1, Qs0, Ds0, kb + 2 < KB);
    }
#undef KSTEP
#undef STAGE

    // epilogue (verbatim R4, verified). C layout: col = lane&15,
    // row = (lane>>4)*4 + reg (16x16 shape)
    const int dp = dper[0];
#pragma unroll
    for (int i = 0; i < 4; ++i)
#pragma unroll
        for (int r = 0; r < 4; ++r) {
            const int gr   = qbase + (wave >> 1) * 64 + 16 * i + 4 * lquad + r;
            const int pcol = gr * dp - dbase;   // local col of positive, if here
            float e = 0.0f;
#pragma unroll
            for (int j = 0; j < 4; ++j) {
                float v = acc[i * 4 + j][r];
                if ((wave & 1) * 64 + 16 * j + lm == pcol) pos[gr] = v * TEMP_INV;
                e += __expf(v * TEMP_INV);
            }
            e += __shfl_xor(e, 1);
            e += __shfl_xor(e, 2);
            e += __shfl_xor(e, 4);
            e += __shfl_xor(e, 8);
            if (lm == 0) atomicAdd(&rowsum[gr], e);
        }
}

// ---------------- final: loss = sum(log(rowsum) - pos)/B ----------------
__global__ void final_kernel(const float* __restrict__ rowsum,
                             const float* __restrict__ pos,
                             float* __restrict__ out, int B) {
    __shared__ float red[16];
    int tid = threadIdx.x;   // 1024 threads
    float s = 0.0f;
    for (int i = tid; i < B; i += blockDim.x)
        s += __logf(rowsum[i]) - pos[i];
    s += __shfl_xor(s, 32);
    s += __shfl_xor(s, 16);
    s += __shfl_xor(s, 8);
    s += __shfl_xor(s, 4);
    s += __shfl_xor(s, 2);
    s += __shfl_xor(s, 1);
    int w = tid >> 6, l = tid & 63;
    if (l == 0) red[w] = s;
    __syncthreads();
    if (tid == 0) {
        float t = 0.0f;
        int nw = blockDim.x >> 6;
        for (int i = 0; i < nw; ++i) t += red[i];
        out[0] = t / (float)B;
    }
}

extern "C" void kernel_launch(void* const* d_in, const int* in_sizes, int n_in,
                              void* d_out, int out_size, void* d_ws, size_t ws_size,
                              hipStream_t stream) {
    const float* Q   = (const float*)d_in[0];
    const float* Dm  = (const float*)d_in[1];
    const int* dper  = (const int*)d_in[2];
    float* out = (float*)d_out;

    const int DIM  = 1024;
    const int B    = in_sizes[0] / DIM;   // 4096
    const int Ntot = in_sizes[1] / DIM;   // 8192

    unsigned int* Q8 = (unsigned int*)d_ws;
    unsigned int* D8 = Q8 + (size_t)B * DIM / 4;
    float* rowsum = (float*)(D8 + (size_t)Ntot * DIM / 4);
    float* pos = rowsum + B;

    const int qSlots = B * DIM / 16;            // 262144
    const int dSlots = Ntot * DIM / 16;         // 524288
    cvt_kernel<<<(qSlots + dSlots) / 256, 256, 0, stream>>>(
        Q, Dm, Q8, D8, rowsum, qSlots, B, DIM);

    dim3 grid(B / 128, Ntot / 128);
    gemm_expsum_kernel<<<grid, 256, 0, stream>>>(Q8, D8, dper, rowsum, pos, DIM);

    final_kernel<<<1, 1024, 0, stream>>>(rowsum, pos, out, B);
}

// Round 3
// 128.753 us; speedup vs baseline: 1.4151x; 1.0627x over previous
//
#include <hip/hip_runtime.h>

// InfoNCE loss:
//   loss = (1/B) * sum_i [ log(sum_j exp(Q_i . D_j / T)) - Q_i . D_{i*dp} / T ]
//
// R7 = R4's gemm structure VERBATIM (verified 45.7us, absmax 0.0) + two
// low-risk changes:
//
//  1. GEMM grid: 1D (2048 blocks) with bijective XCD-aware swizzle.
//     f%8 = XCD (HW round-robin); each XCD gets a 16x16 sub-tile of the
//     (32 bx x 64 by) block grid:
//        xcd = f&7; sub = f>>3;
//        bx = (xcd&1)*16 + (sub&15);  by = (xcd>>1)*16 + (sub>>4);
//     Per-XCD working set = 2MB Q-slab + 2MB D-slab = 4MB = one XCD L2.
//     bx fast-varying: 16 consecutive blocks share one D-panel and re-sweep
//     the same Q-slab -> per-K-step staging fetches become local-L2 hits
//     (~200cy) instead of L3/HBM (~500-900cy), shrinking the per-step
//     vmcnt(0) drain that R4 pays at its first __syncthreads.
//     (R5/R6 post-mortem: in-block pipelining that cut blocks/CU from ~2.3
//     to ~1.5 lost more TLP cover than it gained; so attack latency L
//     itself, keep the 2-block alternation.)
//
//  2. cvt: within each 64-slot (1KB) output chunk, permute which THREAD
//     produces which slot (l -> ((l&3)<<4)|(l>>2), bijection). Chunk
//     contents unchanged; 4 consecutive lanes read 256B contiguous.
//
// Tiled global layout (per matrix, unchanged): for 128-row block R, 128-wide
// k-block k0b: 16KB image = 16 chunks x 1KB. Chunk c = rg*2 + kh (rg=0..7
// 16-row group, kh=0..1 64-col half); slot l (16B) holds
//   X[R*128 + rg*16 + (l&15)][k0b*128 + kh*64 + (l>>4)*16 .. +16]   (fp8)
//
// ws layout (~12.1 MB):
//   [0)       Q8  B*K fp8     (4 MB)
//   [B*K)     D8  N*K fp8     (8 MB)
//   [+N*K)    rowsum B f32    (16 KB)  zeroed by cvt kernel
//   [+B*4)    pos    B f32    (16 KB)  written by gemm epilogue

#define TEMP_INV 50.0f
#define PRESCALE 16.0f
#define SCALE_BYTE 123   // e8m0: 2^(123-127) = 2^-4 per operand

typedef int   i32x4 __attribute__((ext_vector_type(4)));
typedef int   i32x8 __attribute__((ext_vector_type(8)));
typedef float f32x4 __attribute__((ext_vector_type(4)));

// ---------------- fp32 -> fp8 e4m3 (x16), pre-tiled; zero rowsum ----------
__global__ void cvt_kernel(const float* __restrict__ Q, const float* __restrict__ Dm,
                           unsigned int* __restrict__ Q8, unsigned int* __restrict__ D8,
                           float* __restrict__ rowsum, int qSlots, int B, int K) {
    const int gid = blockIdx.x * blockDim.x + threadIdx.x;
    if (gid < B) rowsum[gid] = 0.0f;
    const float* src;
    unsigned int* dst;
    int s;
    if (gid < qSlots) { src = Q;  dst = Q8; s = gid; }
    else              { src = Dm; dst = D8; s = gid - qSlots; }
    // Slot permutation within the 64-slot chunk: lane l handles slot
    // ((l&3)<<4)|(l>>2).  Reads coalesce to 256B runs; the wave still
    // writes the same contiguous 1KB chunk.
    {
        const int l0 = s & 63;
        s = (s & ~63) | (((l0 & 3) << 4) | (l0 >> 2));
    }
    const int l   = s & 63;
    const int c   = (s >> 6) & 15;
    const int k0b = (s >> 10) & 7;
    const int R   = s >> 13;
    const int row = R * 128 + (c >> 1) * 16 + (l & 15);
    const int k   = k0b * 128 + (c & 1) * 64 + (l >> 4) * 16;
    const float* p = src + (size_t)row * K + k;
    unsigned int w[4];
#pragma unroll
    for (int d = 0; d < 4; ++d) {
        float4 v = *(const float4*)(p + d * 4);
        int t = __builtin_amdgcn_cvt_pk_fp8_f32(v.x * PRESCALE, v.y * PRESCALE, 0, false);
        t = __builtin_amdgcn_cvt_pk_fp8_f32(v.z * PRESCALE, v.w * PRESCALE, t, true);
        w[d] = (unsigned int)t;
    }
    *(uint4*)(dst + (size_t)s * 4) = make_uint4(w[0], w[1], w[2], w[3]);
}

// ---------------- fused MX-fp8 GEMM + row sum-exp + pos extraction --------
// grid: 1D 2048 blocks (XCD-swizzled -> bx in [0,32), by in [0,64)),
// 256 threads (4 waves, 2x2 wave grid), BK=128. R4 loop structure.
__global__ __launch_bounds__(256, 2) void gemm_expsum_kernel(
        const unsigned int* __restrict__ Q8, const unsigned int* __restrict__ D8,
        const int* __restrict__ dper,
        float* __restrict__ rowsum, float* __restrict__ pos, int K) {
    __shared__ unsigned int Qs[4096];   // 16KB fragment-order image
    __shared__ unsigned int Ds[4096];

    const int tid   = threadIdx.x;
    const int wave  = tid >> 6;
    const int lane  = tid & 63;
    const int lquad = lane >> 4;
    const int lm    = lane & 15;

    // XCD-aware bijective swizzle: 2048 = 8 XCDs x (16 bx x 16 by) sub-tiles.
    const int f   = blockIdx.x;
    const int xcd = f & 7;
    const int sub = f >> 3;
    const int bx  = (xcd & 1) * 16 + (sub & 15);
    const int by  = (xcd >> 1) * 16 + (sub >> 4);

    const int qbase = bx * 128;
    const int dbase = by * 128;
    const int KB    = K >> 7;           // 8 k-blocks

    // fragment-read dword offsets: chunk(rg, kh=lquad>>1)*256 + slot*4,
    // slot = ((lquad&1)*2 + t)*16 + lm
    const int slotofs = ((lquad & 1) * 32 + lm) * 4;   // t=0; t=1 adds 64
    const int aofs = ((wave >> 1) * 8 + (lquad >> 1)) * 256 + slotofs;
    const int bofs = ((wave & 1) * 8 + (lquad >> 1)) * 256 + slotofs;

    const unsigned int* Qg = Q8 + (size_t)bx * KB * 4096;
    const unsigned int* Dg = D8 + (size_t)by * KB * 4096;

    f32x4 acc[16];
#pragma unroll
    for (int t = 0; t < 16; ++t) acc[t] = (f32x4){0.f, 0.f, 0.f, 0.f};

    for (int kb = 0; kb < KB; ++kb) {
#pragma unroll
        for (int q = 0; q < 4; ++q) {
            const int c = wave * 4 + q;
            const unsigned int* g1 = Qg + kb * 4096 + c * 256 + lane * 4;
            __builtin_amdgcn_global_load_lds(
                (const __attribute__((address_space(1))) void*)g1,
                (__attribute__((address_space(3))) void*)(Qs + c * 256 + lane * 4),
                16, 0, 0);
            const unsigned int* g2 = Dg + kb * 4096 + c * 256 + lane * 4;
            __builtin_amdgcn_global_load_lds(
                (const __attribute__((address_space(1))) void*)g2,
                (__attribute__((address_space(3))) void*)(Ds + c * 256 + lane * 4),
                16, 0, 0);
        }
        __syncthreads();   // drains vmcnt -> LDS tiles ready

        i32x8 a8[4], b8[4];
#pragma unroll
        for (int i = 0; i < 4; ++i) {
            i32x4 lo = *(const i32x4*)(Qs + aofs + i * 512);
            i32x4 hi = *(const i32x4*)(Qs + aofs + i * 512 + 64);
            a8[i] = __builtin_shufflevector(lo, hi, 0, 1, 2, 3, 4, 5, 6, 7);
        }
#pragma unroll
        for (int j = 0; j < 4; ++j) {
            i32x4 lo = *(const i32x4*)(Ds + bofs + j * 512);
            i32x4 hi = *(const i32x4*)(Ds + bofs + j * 512 + 64);
            b8[j] = __builtin_shufflevector(lo, hi, 0, 1, 2, 3, 4, 5, 6, 7);
        }
#pragma unroll
        for (int i = 0; i < 4; ++i)
#pragma unroll
            for (int j = 0; j < 4; ++j)
                acc[i * 4 + j] = __builtin_amdgcn_mfma_scale_f32_16x16x128_f8f6f4(
                    a8[i], b8[j], acc[i * 4 + j], 0, 0, 0, SCALE_BYTE, 0, SCALE_BYTE);
        __syncthreads();   // all waves done reading before next stage
    }

    // epilogue (verbatim R4, verified). C layout: col = lane&15,
    // row = (lane>>4)*4 + reg (16x16 shape)
    const int dp = dper[0];
#pragma unroll
    for (int i = 0; i < 4; ++i)
#pragma unroll
        for (int r = 0; r < 4; ++r) {
            const int gr   = qbase + (wave >> 1) * 64 + 16 * i + 4 * lquad + r;
            const int pcol = gr * dp - dbase;   // local col of positive, if here
            float e = 0.0f;
#pragma unroll
            for (int j = 0; j < 4; ++j) {
                float v = acc[i * 4 + j][r];
                if ((wave & 1) * 64 + 16 * j + lm == pcol) pos[gr] = v * TEMP_INV;
                e += __expf(v * TEMP_INV);
            }
            e += __shfl_xor(e, 1);
            e += __shfl_xor(e, 2);
            e += __shfl_xor(e, 4);
            e += __shfl_xor(e, 8);
            if (lm == 0) atomicAdd(&rowsum[gr], e);
        }
}

// ---------------- final: loss = sum(log(rowsum) - pos)/B ----------------
__global__ void final_kernel(const float* __restrict__ rowsum,
                             const float* __restrict__ pos,
                             float* __restrict__ out, int B) {
    __shared__ float red[16];
    int tid = threadIdx.x;   // 1024 threads
    float s = 0.0f;
    for (int i = tid; i < B; i += blockDim.x)
        s += __logf(rowsum[i]) - pos[i];
    s += __shfl_xor(s, 32);
    s += __shfl_xor(s, 16);
    s += __shfl_xor(s, 8);
    s += __shfl_xor(s, 4);
    s += __shfl_xor(s, 2);
    s += __shfl_xor(s, 1);
    int w = tid >> 6, l = tid & 63;
    if (l == 0) red[w] = s;
    __syncthreads();
    if (tid == 0) {
        float t = 0.0f;
        int nw = blockDim.x >> 6;
        for (int i = 0; i < nw; ++i) t += red[i];
        out[0] = t / (float)B;
    }
}

extern "C" void kernel_launch(void* const* d_in, const int* in_sizes, int n_in,
                              void* d_out, int out_size, void* d_ws, size_t ws_size,
                              hipStream_t stream) {
    const float* Q   = (const float*)d_in[0];
    const float* Dm  = (const float*)d_in[1];
    const int* dper  = (const int*)d_in[2];
    float* out = (float*)d_out;

    const int DIM  = 1024;
    const int B    = in_sizes[0] / DIM;   // 4096
    const int Ntot = in_sizes[1] / DIM;   // 8192

    unsigned int* Q8 = (unsigned int*)d_ws;
    unsigned int* D8 = Q8 + (size_t)B * DIM / 4;
    float* rowsum = (float*)(D8 + (size_t)Ntot * DIM / 4);
    float* pos = rowsum + B;

    const int qSlots = B * DIM / 16;            // 262144
    const int dSlots = Ntot * DIM / 16;         // 524288
    cvt_kernel<<<(qSlots + dSlots) / 256, 256, 0, stream>>>(
        Q, Dm, Q8, D8, rowsum, qSlots, B, DIM);

    const int nblk = (B / 128) * (Ntot / 128);  // 2048 = 8 * 256
    gemm_expsum_kernel<<<nblk, 256, 0, stream>>>(Q8, D8, dper, rowsum, pos, DIM);

    final_kernel<<<1, 1024, 0, stream>>>(rowsum, pos, out, B);
}